// Round 4
// baseline (1060.907 us; speedup 1.0000x reference)
//
#include <hip/hip_runtime.h>

#define NBATCH 8
#define CIN    256
#define CQ     64
#define HW     4096
#define NT     (HW / 64)

typedef __attribute__((ext_vector_type(8))) _Float16 f16x8;
typedef __attribute__((ext_vector_type(4))) _Float16 f16x4;
typedef __attribute__((ext_vector_type(4))) float    f32x4;
typedef _Float16 half_t;

#define MFMA_F16(a, b, c) __builtin_amdgcn_mfma_f32_16x16x32_f16((a), (b), (c), 0, 0, 0)

// ---------------- k_prep: V (ref, src) fp32 -> fp16, layout [t][n][c][p], t0=ref ----------
__global__ __launch_bounds__(256) void k_prep(
    const float* __restrict__ reff, const float* __restrict__ srcf,
    half_t* __restrict__ vh)
{
    const size_t half_n = (size_t)NBATCH * CIN * HW;
    const size_t i4 = ((size_t)blockIdx.x * 256 + threadIdx.x) * 4;
    float4 v = (i4 < half_n) ? *(const float4*)(reff + i4)
                             : *(const float4*)(srcf + (i4 - half_n));
    f16x4 h;
    h[0] = (half_t)v.x; h[1] = (half_t)v.y; h[2] = (half_t)v.z; h[3] = (half_t)v.w;
    *(f16x4*)(vh + i4) = h;
}

// ---------------- k_query: q = conv1x1(src), store transposed qt[n][p][c] fp16 hi/lo ------
__global__ __launch_bounds__(256) void k_query(
    const float* __restrict__ src, const float* __restrict__ w,
    half_t* __restrict__ qth, half_t* __restrict__ qtl)
{
    __shared__ float ws[CIN][36];
    const int bid = blockIdx.x;
    const int n  = bid >> 5;
    const int pt = (bid >> 1) & 15;
    const int og = bid & 1;
    const int tid = threadIdx.x;
    for (int r = 0; r < 32; ++r) {
        int idx = r * 256 + tid;
        int oo = idx >> 8, c = idx & 255;
        ws[c][oo] = w[(og * 32 + oo) * CIN + c];
    }
    __syncthreads();
    const int p = pt * 256 + tid;
    const float* srcn = src + (size_t)n * CIN * HW + p;
    float acc[32];
#pragma unroll
    for (int oo = 0; oo < 32; ++oo) acc[oo] = 0.f;
#pragma unroll 4
    for (int c = 0; c < CIN; ++c) {
        float xv = srcn[(size_t)c * HW];
#pragma unroll
        for (int gg = 0; gg < 8; ++gg) {
            float4 w4 = *(const float4*)&ws[c][gg * 4];
            acc[gg * 4 + 0] = fmaf(w4.x, xv, acc[gg * 4 + 0]);
            acc[gg * 4 + 1] = fmaf(w4.y, xv, acc[gg * 4 + 1]);
            acc[gg * 4 + 2] = fmaf(w4.z, xv, acc[gg * 4 + 2]);
            acc[gg * 4 + 3] = fmaf(w4.w, xv, acc[gg * 4 + 3]);
        }
    }
    const size_t base = ((size_t)n * HW + p) * CQ + og * 32;
    half_t hb[32], lb[32];
#pragma unroll
    for (int oo = 0; oo < 32; ++oo) {
        hb[oo] = (half_t)acc[oo];
        lb[oo] = (half_t)(acc[oo] - (float)hb[oo]);
    }
#pragma unroll
    for (int v = 0; v < 4; ++v) {
        *(f16x8*)(qth + base + v * 8) = *(f16x8*)&hb[v * 8];
        *(f16x8*)(qtl + base + v * 8) = *(f16x8*)&lb[v * 8];
    }
}

// ---------------- k_apply: pipelined fused flash attention + blend + concat --------------
// Per iteration t (ONE barrier):
//   [rescale acc by FS(t-1), rare] -> MFMA cluster: PV(t-1) then S(t)
//   -> issue QJ(t+1) + V(t) global loads -> softmax(t) VALU -> P/FS/QJ writes -> barrier
// Softmax is off the MFMA critical path: PV(t-1) fills the pipe while softmax(t) runs.
__global__ __launch_bounds__(256, 3) void k_apply(
    const half_t* __restrict__ qh, const half_t* __restrict__ ql,
    const half_t* __restrict__ vhp, const float* __restrict__ reff,
    const float* __restrict__ maskp, float* __restrict__ out)
{
    __shared__ __align__(16) half_t QJ[2][64 * 64];  // j-side Q, HI plane only, swizzled
    __shared__ __align__(16) half_t P[2][64 * 64];   // P[i_local][j_local], swizzled
    __shared__ float FS[2][64];
    __shared__ float LS[64];

    const int bid = blockIdx.x;
    const int logical = (bid & 7) * 128 + (bid >> 3);   // XCD-contiguous groups
    const int itile = logical & 63;
    const int chunk = (logical >> 6) & 1;
    const int n     = logical >> 7;
    const int i0 = itile * 64;
    const int tid = threadIdx.x;
    const int lane = tid & 63;
    const int wv = tid >> 6;
    const int r16 = lane & 15;
    const int g = lane >> 4;
    const int rl = (lane >> 3) & 7;   // staging row-local
    const int cb = lane & 7;          // staging 16B-chunk index

    const half_t* qhn = qh + (size_t)n * HW * CQ;
    const half_t* qln = ql + (size_t)n * HW * CQ;
    const half_t* V = vhp + ((size_t)chunk * NBATCH + n) * CIN * HW;

    // persistent B-frags (i-side, hi+lo): i = i0 + wv*16 + r16
    const int iq = i0 + wv * 16 + r16;
    f16x8 qbh[2], qbl[2];
#pragma unroll
    for (int ks = 0; ks < 2; ++ks) {
        qbh[ks] = *(const f16x8*)(qhn + (size_t)iq * CQ + ks * 32 + g * 8);
        qbl[ks] = *(const f16x8*)(qln + (size_t)iq * CQ + ks * 32 + g * 8);
    }

    f32x4 acc[4][4];   // [cf][fi]: c = wv*64+cf*16+g*4+r, i = i0+fi*16+r16
#pragma unroll
    for (int a = 0; a < 4; ++a)
#pragma unroll
        for (int b = 0; b < 4; ++b) acc[a][b] = (f32x4){0.f, 0.f, 0.f, 0.f};
    float M_run = -1e30f, l_run = 0.f;
    const int c0 = wv * 64;
    f16x8 vfrag[4][2];   // V(t) fragments, consumed by PV at iter t+1

    // ---- prologue: stage QJ[0] (hi plane)
    {
        f16x8 s0 = *(const f16x8*)(qhn + (size_t)(wv * 16 + rl) * CQ + cb * 8);
        f16x8 s1 = *(const f16x8*)(qhn + (size_t)(wv * 16 + 8 + rl) * CQ + cb * 8);
        *(f16x8*)&QJ[0][(wv * 16 + rl) * 64 + ((cb * 8) ^ (rl * 8))] = s0;
        *(f16x8*)&QJ[0][(wv * 16 + 8 + rl) * 64 + ((cb * 8) ^ (rl * 8))] = s1;
    }
    __syncthreads();

#pragma unroll 2
    for (int jt = 0; jt < NT; ++jt) {
        const int j0 = jt * 64;
        const int buf = jt & 1;
        const int jn = (jt + 1 < NT) ? (jt + 1) * 64 : 0;

        // ---- rare rescale of acc by FS(t-1), must precede PV(t-1)
        if (jt > 0) {
            float fr0 = FS[buf ^ 1][r16];
            float fr1 = FS[buf ^ 1][16 + r16];
            float fr2 = FS[buf ^ 1][32 + r16];
            float fr3 = FS[buf ^ 1][48 + r16];
            if (!__all(fr0 + fr1 + fr2 + fr3 == 4.0f)) {
#pragma unroll
                for (int cf = 0; cf < 4; ++cf) {
                    acc[cf][0] *= fr0;
                    acc[cf][1] *= fr1;
                    acc[cf][2] *= fr2;
                    acc[cf][3] *= fr3;
                }
            }
        }

        __builtin_amdgcn_s_setprio(1);
        // ---- PV(t-1): P[buf^1] x vfrag(V(t-1))  (skipped at t=0)
        if (jt > 0) {
#pragma unroll
            for (int ks = 0; ks < 2; ++ks) {
                f16x8 pf[4];
#pragma unroll
                for (int fi = 0; fi < 4; ++fi) {
                    const int ip = fi * 16 + r16;
                    pf[fi] = *(const f16x8*)&P[buf ^ 1][ip * 64 + ((ks * 32 + g * 8) ^ ((ip & 7) * 8))];
                }
#pragma unroll
                for (int cf = 0; cf < 4; ++cf)
#pragma unroll
                    for (int fi = 0; fi < 4; ++fi)
                        acc[cf][fi] = MFMA_F16(vfrag[cf][ks], pf[fi], acc[cf][fi]);
            }
        }
        // ---- S(t): A = QJ[buf] rows j (hi), B = persistent qb (hi+lo)
        f32x4 sv[4];
#pragma unroll
        for (int f = 0; f < 4; ++f) {
            const int row = f * 16 + r16;
            const int sw = (row & 7) * 8;
            f16x8 ah0 = *(const f16x8*)&QJ[buf][row * 64 + ((g * 8) ^ sw)];
            f16x8 ah1 = *(const f16x8*)&QJ[buf][row * 64 + ((32 + g * 8) ^ sw)];
            f32x4 s = {0.f, 0.f, 0.f, 0.f};
            s = MFMA_F16(ah0, qbh[0], s);
            s = MFMA_F16(ah1, qbh[1], s);
            s = MFMA_F16(ah0, qbl[0], s);
            s = MFMA_F16(ah1, qbl[1], s);
            sv[f] = s;
        }
        __builtin_amdgcn_s_setprio(0);

        // ---- issue next-tile loads (age through softmax + barrier)
        f16x8 stg0 = *(const f16x8*)(qhn + (size_t)(jn + wv * 16 + rl) * CQ + cb * 8);
        f16x8 stg1 = *(const f16x8*)(qhn + (size_t)(jn + wv * 16 + 8 + rl) * CQ + cb * 8);
#pragma unroll
        for (int cf = 0; cf < 4; ++cf)
#pragma unroll
            for (int ks = 0; ks < 2; ++ks)
                vfrag[cf][ks] = *(const f16x8*)(V + (size_t)(c0 + cf * 16 + r16) * HW
                                                + j0 + ks * 32 + g * 8);

        // ---- softmax(t): lane owns i = wv*16 + r16 (16 j values)
        float m_t = sv[0][0];
#pragma unroll
        for (int f = 0; f < 4; ++f)
#pragma unroll
            for (int r = 0; r < 4; ++r) m_t = fmaxf(m_t, sv[f][r]);
        m_t = fmaxf(m_t, __shfl_xor(m_t, 16));
        m_t = fmaxf(m_t, __shfl_xor(m_t, 32));
        const float M_new = (m_t > M_run + 6.0f) ? m_t : M_run;
        const float fsc = __expf(M_run - M_new);
        float psum = 0.f;
#pragma unroll
        for (int f = 0; f < 4; ++f)
#pragma unroll
            for (int r = 0; r < 4; ++r) {
                float ev = __expf(sv[f][r] - M_new);
                sv[f][r] = ev;
                psum += ev;
            }
        psum += __shfl_xor(psum, 16);
        psum += __shfl_xor(psum, 32);
        l_run = l_run * fsc + psum;
        M_run = M_new;

        const int iP = wv * 16 + r16;
        const int swp = (iP & 7) * 8;
#pragma unroll
        for (int f = 0; f < 4; ++f) {
            f16x4 pv;
#pragma unroll
            for (int r = 0; r < 4; ++r) pv[r] = (half_t)sv[f][r];
            *(f16x4*)&P[buf][iP * 64 + ((f * 16 + g * 4) ^ swp)] = pv;
        }
        if (g == 0) FS[buf][iP] = fsc;

        // ---- stage QJ(t+1)
        *(f16x8*)&QJ[buf ^ 1][(wv * 16 + rl) * 64 + ((cb * 8) ^ (rl * 8))] = stg0;
        *(f16x8*)&QJ[buf ^ 1][(wv * 16 + 8 + rl) * 64 + ((cb * 8) ^ (rl * 8))] = stg1;

        __syncthreads();
    }

    // ---- epilogue: final rescale + PV(NT-1)
    {
        const int pb = (NT - 1) & 1;
        float fr0 = FS[pb][r16];
        float fr1 = FS[pb][16 + r16];
        float fr2 = FS[pb][32 + r16];
        float fr3 = FS[pb][48 + r16];
        if (!__all(fr0 + fr1 + fr2 + fr3 == 4.0f)) {
#pragma unroll
            for (int cf = 0; cf < 4; ++cf) {
                acc[cf][0] *= fr0;
                acc[cf][1] *= fr1;
                acc[cf][2] *= fr2;
                acc[cf][3] *= fr3;
            }
        }
#pragma unroll
        for (int ks = 0; ks < 2; ++ks) {
            f16x8 pf[4];
#pragma unroll
            for (int fi = 0; fi < 4; ++fi) {
                const int ip = fi * 16 + r16;
                pf[fi] = *(const f16x8*)&P[pb][ip * 64 + ((ks * 32 + g * 8) ^ ((ip & 7) * 8))];
            }
#pragma unroll
            for (int cf = 0; cf < 4; ++cf)
#pragma unroll
                for (int fi = 0; fi < 4; ++fi)
                    acc[cf][fi] = MFMA_F16(vfrag[cf][ks], pf[fi], acc[cf][fi]);
        }
    }

    // ---- share l across waves, normalize, blend, write
    if (g == 0) LS[wv * 16 + r16] = l_run;
    __syncthreads();
    float linv[4];
#pragma unroll
    for (int fi = 0; fi < 4; ++fi) linv[fi] = 1.0f / LS[fi * 16 + r16];

    const size_t outbase = ((size_t)n * 2 * CIN + (size_t)chunk * CIN) * HW;
#pragma unroll
    for (int fi = 0; fi < 4; ++fi) {
        const int i = i0 + fi * 16 + r16;
        float mk = 0.f;
        if (chunk == 0) mk = maskp[n * HW + i];
#pragma unroll
        for (int cf = 0; cf < 4; ++cf) {
#pragma unroll
            for (int r = 0; r < 4; ++r) {
                const int c = c0 + cf * 16 + g * 4 + r;
                float o = acc[cf][fi][r] * linv[fi];
                if (chunk == 0) {
                    const float rv = reff[((size_t)n * CIN + c) * HW + i];
                    o = (1.f - mk) * o + mk * rv;
                }
                out[outbase + (size_t)c * HW + i] = o;
            }
        }
    }
}

extern "C" void kernel_launch(void* const* d_in, const int* in_sizes, int n_in,
                              void* d_out, int out_size, void* d_ws, size_t ws_size,
                              hipStream_t stream) {
    const float* src_mask = (const float*)d_in[0];
    const float* src_feat = (const float*)d_in[1];
    const float* ref_feat = (const float*)d_in[2];
    const float* conv_w   = (const float*)d_in[3];
    float* out = (float*)d_out;

    char* ws = (char*)d_ws;
    const size_t qbytes = (size_t)NBATCH * HW * CQ * sizeof(half_t);          // 4 MB
    const size_t vbytes = (size_t)2 * NBATCH * CIN * HW * sizeof(half_t);     // 33.6 MB
    half_t* qth = (half_t*)ws;  ws += qbytes;
    half_t* qtl = (half_t*)ws;  ws += qbytes;
    half_t* vh  = (half_t*)ws;  ws += vbytes;

    k_prep<<<dim3(16384), dim3(256), 0, stream>>>(ref_feat, src_feat, vh);
    k_query<<<dim3(256), dim3(256), 0, stream>>>(src_feat, conv_w, qth, qtl);
    k_apply<<<dim3(1024), dim3(256), 0, stream>>>(qth, qtl, vh, ref_feat,
                                                  src_mask, out);
}

// Round 5
// 451.189 us; speedup vs baseline: 2.3514x; 2.3514x over previous
//
#include <hip/hip_runtime.h>

#define NBATCH 8
#define CIN    256
#define CQ     64
#define HW     4096
#define NT     (HW / 64)
#define MARGIN 4.0f

typedef __attribute__((ext_vector_type(8))) _Float16 f16x8;
typedef __attribute__((ext_vector_type(4))) _Float16 f16x4;
typedef __attribute__((ext_vector_type(4))) float    f32x4;
typedef _Float16 half_t;

#define MFMA_F16(a, b, c) __builtin_amdgcn_mfma_f32_16x16x32_f16((a), (b), (c), 0, 0, 0)

// ---------------- k_prep: V (ref, src) fp32 -> fp16, layout [t][n][c][p], t0=ref ----------
__global__ __launch_bounds__(256) void k_prep(
    const float* __restrict__ reff, const float* __restrict__ srcf,
    half_t* __restrict__ vh)
{
    const size_t half_n = (size_t)NBATCH * CIN * HW;
    const size_t i4 = ((size_t)blockIdx.x * 256 + threadIdx.x) * 4;
    float4 v = (i4 < half_n) ? *(const float4*)(reff + i4)
                             : *(const float4*)(srcf + (i4 - half_n));
    f16x4 h;
    h[0] = (half_t)v.x; h[1] = (half_t)v.y; h[2] = (half_t)v.z; h[3] = (half_t)v.w;
    *(f16x4*)(vh + i4) = h;
}

// ---------------- k_query: q = conv1x1(src), store transposed qt[n][p][c] fp16 hi/lo ------
__global__ __launch_bounds__(256) void k_query(
    const float* __restrict__ src, const float* __restrict__ w,
    half_t* __restrict__ qth, half_t* __restrict__ qtl)
{
    __shared__ float ws[CIN][36];
    const int bid = blockIdx.x;
    const int n  = bid >> 5;
    const int pt = (bid >> 1) & 15;
    const int og = bid & 1;
    const int tid = threadIdx.x;
    for (int r = 0; r < 32; ++r) {
        int idx = r * 256 + tid;
        int oo = idx >> 8, c = idx & 255;
        ws[c][oo] = w[(og * 32 + oo) * CIN + c];
    }
    __syncthreads();
    const int p = pt * 256 + tid;
    const float* srcn = src + (size_t)n * CIN * HW + p;
    float acc[32];
#pragma unroll
    for (int oo = 0; oo < 32; ++oo) acc[oo] = 0.f;
#pragma unroll 4
    for (int c = 0; c < CIN; ++c) {
        float xv = srcn[(size_t)c * HW];
#pragma unroll
        for (int gg = 0; gg < 8; ++gg) {
            float4 w4 = *(const float4*)&ws[c][gg * 4];
            acc[gg * 4 + 0] = fmaf(w4.x, xv, acc[gg * 4 + 0]);
            acc[gg * 4 + 1] = fmaf(w4.y, xv, acc[gg * 4 + 1]);
            acc[gg * 4 + 2] = fmaf(w4.z, xv, acc[gg * 4 + 2]);
            acc[gg * 4 + 3] = fmaf(w4.w, xv, acc[gg * 4 + 3]);
        }
    }
    const size_t base = ((size_t)n * HW + p) * CQ + og * 32;
    half_t hb[32], lb[32];
#pragma unroll
    for (int oo = 0; oo < 32; ++oo) {
        hb[oo] = (half_t)acc[oo];
        lb[oo] = (half_t)(acc[oo] - (float)hb[oo]);
    }
#pragma unroll
    for (int v = 0; v < 4; ++v) {
        *(f16x8*)(qth + base + v * 8) = *(f16x8*)&hb[v * 8];
        *(f16x8*)(qtl + base + v * 8) = *(f16x8*)&lb[v * 8];
    }
}

// ---------------- k_apply: fused flash attention, fixed per-row max M_i = |q_i|^2 + 4 ----
// One barrier per j-tile. Per iter t:
//   issue V(t)+QJ(t+1) loads -> S(t) MFMA -> softmax-lite (exp only, per-lane l) ->
//   P(t)/QJ(t+1) writes -> barrier -> PV(t)
// No online max, no rescale: p = exp(s - M_i) is exact after final l-normalization.
__global__ __launch_bounds__(256, 3) void k_apply(
    const half_t* __restrict__ qh, const half_t* __restrict__ ql,
    const half_t* __restrict__ vhp, const float* __restrict__ reff,
    const float* __restrict__ maskp, float* __restrict__ out)
{
    __shared__ __align__(16) half_t QJ[2][64 * 64];  // j-side Q, HI plane only, swizzled
    __shared__ __align__(16) half_t P[2][64 * 64];   // P[i_local][j_local], swizzled
    __shared__ float LS[64];

    const int bid = blockIdx.x;
    const int logical = (bid & 7) * 128 + (bid >> 3);   // XCD-contiguous groups
    const int itile = logical & 63;
    const int chunk = (logical >> 6) & 1;
    const int n     = logical >> 7;
    const int i0 = itile * 64;
    const int tid = threadIdx.x;
    const int lane = tid & 63;
    const int wv = tid >> 6;
    const int r16 = lane & 15;
    const int g = lane >> 4;
    const int rl = (lane >> 3) & 7;   // staging row-local
    const int cb = lane & 7;          // staging 16B-chunk index

    const half_t* qhn = qh + (size_t)n * HW * CQ;
    const half_t* qln = ql + (size_t)n * HW * CQ;
    const half_t* V = vhp + ((size_t)chunk * NBATCH + n) * CIN * HW;

    // persistent B-frags (i-side, hi+lo): i = i0 + wv*16 + r16
    const int iq = i0 + wv * 16 + r16;
    f16x8 qbh[2], qbl[2];
#pragma unroll
    for (int ks = 0; ks < 2; ++ks) {
        qbh[ks] = *(const f16x8*)(qhn + (size_t)iq * CQ + ks * 32 + g * 8);
        qbl[ks] = *(const f16x8*)(qln + (size_t)iq * CQ + ks * 32 + g * 8);
    }
    // M_i = s_ii + MARGIN, s_ii = sum_k h_k*h_k + h_k*l_k  (matches S-MFMA math at j=i)
    float mpart = 0.f;
#pragma unroll
    for (int ks = 0; ks < 2; ++ks)
#pragma unroll
        for (int e = 0; e < 8; ++e) {
            const float h = (float)qbh[ks][e];
            const float l = (float)qbl[ks][e];
            mpart += h * h + h * l;
        }
    mpart += __shfl_xor(mpart, 16);
    mpart += __shfl_xor(mpart, 32);
    const float Mi = mpart + MARGIN;

    f32x4 acc[4][4];   // [cf][fi]: c = wv*64+cf*16+g*4+r, i = i0+fi*16+r16
#pragma unroll
    for (int a = 0; a < 4; ++a)
#pragma unroll
        for (int b = 0; b < 4; ++b) acc[a][b] = (f32x4){0.f, 0.f, 0.f, 0.f};
    float l_loc = 0.f;   // per-lane partial of l_i (i = wv*16+r16), reduced at epilogue
    const int c0 = wv * 64;

    // ---- prologue: stage QJ[0] (hi plane)
    {
        f16x8 s0 = *(const f16x8*)(qhn + (size_t)(wv * 16 + rl) * CQ + cb * 8);
        f16x8 s1 = *(const f16x8*)(qhn + (size_t)(wv * 16 + 8 + rl) * CQ + cb * 8);
        *(f16x8*)&QJ[0][(wv * 16 + rl) * 64 + ((cb * 8) ^ (rl * 8))] = s0;
        *(f16x8*)&QJ[0][(wv * 16 + 8 + rl) * 64 + ((cb * 8) ^ (rl * 8))] = s1;
    }
    __syncthreads();

#pragma unroll 1
    for (int jt = 0; jt < NT; ++jt) {
        const int j0 = jt * 64;
        const int buf = jt & 1;
        const int jn = (jt + 1 < NT) ? (jt + 1) * 64 : 0;

        // ---- issue V(t) loads (consumed after the barrier, this iteration)
        f16x8 vfrag[4][2];
#pragma unroll
        for (int cf = 0; cf < 4; ++cf)
#pragma unroll
            for (int ks = 0; ks < 2; ++ks)
                vfrag[cf][ks] = *(const f16x8*)(V + (size_t)(c0 + cf * 16 + r16) * HW
                                                + j0 + ks * 32 + g * 8);
        // ---- issue QJ(t+1) staging loads (consumed pre-barrier, this iteration)
        f16x8 stg0 = *(const f16x8*)(qhn + (size_t)(jn + wv * 16 + rl) * CQ + cb * 8);
        f16x8 stg1 = *(const f16x8*)(qhn + (size_t)(jn + wv * 16 + 8 + rl) * CQ + cb * 8);

        // ---- S(t): A = QJ[buf] rows j (hi), B = persistent qb (hi+lo)
        __builtin_amdgcn_s_setprio(1);
        f32x4 sv[4];
#pragma unroll
        for (int f = 0; f < 4; ++f) {
            const int row = f * 16 + r16;
            const int sw = (row & 7) * 8;
            f16x8 ah0 = *(const f16x8*)&QJ[buf][row * 64 + ((g * 8) ^ sw)];
            f16x8 ah1 = *(const f16x8*)&QJ[buf][row * 64 + ((32 + g * 8) ^ sw)];
            f32x4 s = {0.f, 0.f, 0.f, 0.f};
            s = MFMA_F16(ah0, qbh[0], s);
            s = MFMA_F16(ah1, qbh[1], s);
            s = MFMA_F16(ah0, qbl[0], s);
            s = MFMA_F16(ah1, qbl[1], s);
            sv[f] = s;
        }
        __builtin_amdgcn_s_setprio(0);

        // ---- softmax-lite: p = exp(s - Mi); accumulate per-lane l (no cross-lane ops)
        const int iP = wv * 16 + r16;
        const int swp = (iP & 7) * 8;
#pragma unroll
        for (int f = 0; f < 4; ++f) {
            f16x4 pv;
#pragma unroll
            for (int r = 0; r < 4; ++r) {
                const float ev = __expf(sv[f][r] - Mi);
                l_loc += ev;
                pv[r] = (half_t)ev;
            }
            *(f16x4*)&P[buf][iP * 64 + ((f * 16 + g * 4) ^ swp)] = pv;
        }

        // ---- stage QJ(t+1)
        *(f16x8*)&QJ[buf ^ 1][(wv * 16 + rl) * 64 + ((cb * 8) ^ (rl * 8))] = stg0;
        *(f16x8*)&QJ[buf ^ 1][(wv * 16 + 8 + rl) * 64 + ((cb * 8) ^ (rl * 8))] = stg1;

        __syncthreads();

        // ---- PV(t): P[buf] x V(t)
        __builtin_amdgcn_s_setprio(1);
#pragma unroll
        for (int ks = 0; ks < 2; ++ks) {
            f16x8 pf[4];
#pragma unroll
            for (int fi = 0; fi < 4; ++fi) {
                const int ip = fi * 16 + r16;
                pf[fi] = *(const f16x8*)&P[buf][ip * 64 + ((ks * 32 + g * 8) ^ ((ip & 7) * 8))];
            }
#pragma unroll
            for (int cf = 0; cf < 4; ++cf)
#pragma unroll
                for (int fi = 0; fi < 4; ++fi)
                    acc[cf][fi] = MFMA_F16(vfrag[cf][ks], pf[fi], acc[cf][fi]);
        }
        __builtin_amdgcn_s_setprio(0);
    }

    // ---- epilogue: reduce l across g-lanes, share across waves, normalize, blend, write
    l_loc += __shfl_xor(l_loc, 16);
    l_loc += __shfl_xor(l_loc, 32);
    if (g == 0) LS[wv * 16 + r16] = l_loc;
    __syncthreads();
    float linv[4];
#pragma unroll
    for (int fi = 0; fi < 4; ++fi) linv[fi] = 1.0f / LS[fi * 16 + r16];

    const size_t outbase = ((size_t)n * 2 * CIN + (size_t)chunk * CIN) * HW;
#pragma unroll
    for (int fi = 0; fi < 4; ++fi) {
        const int i = i0 + fi * 16 + r16;
        float mk = 0.f;
        if (chunk == 0) mk = maskp[n * HW + i];
#pragma unroll
        for (int cf = 0; cf < 4; ++cf) {
#pragma unroll
            for (int r = 0; r < 4; ++r) {
                const int c = c0 + cf * 16 + g * 4 + r;
                float o = acc[cf][fi][r] * linv[fi];
                if (chunk == 0) {
                    const float rv = reff[((size_t)n * CIN + c) * HW + i];
                    o = (1.f - mk) * o + mk * rv;
                }
                out[outbase + (size_t)c * HW + i] = o;
            }
        }
    }
}

extern "C" void kernel_launch(void* const* d_in, const int* in_sizes, int n_in,
                              void* d_out, int out_size, void* d_ws, size_t ws_size,
                              hipStream_t stream) {
    const float* src_mask = (const float*)d_in[0];
    const float* src_feat = (const float*)d_in[1];
    const float* ref_feat = (const float*)d_in[2];
    const float* conv_w   = (const float*)d_in[3];
    float* out = (float*)d_out;

    char* ws = (char*)d_ws;
    const size_t qbytes = (size_t)NBATCH * HW * CQ * sizeof(half_t);          // 4 MB
    const size_t vbytes = (size_t)2 * NBATCH * CIN * HW * sizeof(half_t);     // 33.6 MB
    half_t* qth = (half_t*)ws;  ws += qbytes;
    half_t* qtl = (half_t*)ws;  ws += qbytes;
    half_t* vh  = (half_t*)ws;  ws += vbytes;

    k_prep<<<dim3(16384), dim3(256), 0, stream>>>(ref_feat, src_feat, vh);
    k_query<<<dim3(256), dim3(256), 0, stream>>>(src_feat, conv_w, qth, qtl);
    k_apply<<<dim3(1024), dim3(256), 0, stream>>>(qth, qtl, vh, ref_feat,
                                                  src_mask, out);
}